// Round 1
// baseline (36.249 us; speedup 1.0000x reference)
//
#include <hip/hip_runtime.h>
#include <math.h>

// Lanczos-4 8x upsample, fully collapsed:
//   out[i,j] = va(i)*H[r0(i),j] + vb(i)*H[r1(i),j]
//   H[r,j]   = a(j)*img[r,c0(j)] + b(j)*img[r,c1(j)]
// because (1) nearest-gather replicates rows/cols 8x, (2) exact scale 8 ->
// only 8 weight phases, (3) 9 taps span at most 2 source rows/cols.

#define PI_F 3.14159274101257324f   // float32(pi), matches jnp.float32(np.pi)

__device__ __forceinline__ float lanczos_w(int phi, int p) {
    // reference: delta = 1e-8 + idx/1024, idx = phi*128 ; t = delta + (p-4)
    float delta = 1e-8f + (float)phi * 0.125f;
    float t = delta + (float)(p - 4);
    float s  = t * PI_F;        // t*pi
    float s4 = s * 0.25f;       // t*pi/4  (A = 4)
    return (sinf(s) / s) * (sinf(s4) / s4);
}

__global__ __launch_bounds__(256) void lanczos_up8_kernel(
    const float* __restrict__ img, float* __restrict__ out)
{
    const int W = 256, OW = 2048;

    int bid  = blockIdx.x;
    int bc   = bid >> 9;          // channel 0..7  (B*C = 8)
    int rem  = bid & 511;
    int t    = rem >> 1;          // output row group 0..255 (8 rows each)
    int half = rem & 1;           // column half
    int j0   = half << 10;        // 0 or 1024
    int tid  = threadIdx.x;

    __shared__ float imgL[3][256];   // img rows t-1, t, t+1 (clamped)
    __shared__ float Hs[3][1024];    // horizontally filtered rows, this half
    __shared__ float hA[8], hB[8], hS[8];   // horizontal phase weights
    __shared__ float vA[8], vB[8];          // vertical per-row weights
    __shared__ int   vR0[8], vR1[8];        // vertical source-row LDS indices

    // --- stage 3 source rows (coalesced, 1 float/thread/row) ---
    const float* imgBase = img + (size_t)bc * (256 * 256);
    #pragma unroll
    for (int idx = 0; idx < 3; ++idx) {
        int r = t - 1 + idx;
        r = r < 0 ? 0 : (r > 255 ? 255 : r);
        imgL[idx][tid] = imgBase[r * W + tid];
    }

    // --- phase weight tables (one-time, tiny) ---
    if (tid < 8) {
        int phi = tid;
        float w[9];
        float sum = 0.f;
        #pragma unroll
        for (int p = 0; p < 9; ++p) { w[p] = lanczos_w(phi, p); sum += w[p]; }
        int m = (phi + 4) & 7;                 // (j-4)&7 for j==phi (mod 8)
        float wl = 0.f, wr = 0.f;
        #pragma unroll
        for (int p = 0; p < 9; ++p) {
            if (p <= 7 - m) wl += w[p]; else wr += w[p];
        }
        hA[phi] = wl; hB[phi] = wr; hS[phi] = sum;
    } else if (tid < 16) {
        int s = tid - 8;
        int i = (t << 3) + s;
        float va = 0.f, vb = 0.f;
        int r0 = -1, r1 = -1;
        #pragma unroll
        for (int q = 0; q < 9; ++q) {
            int y = i - 4 + q;
            y = y < 0 ? -y : (y > 2047 ? 4094 - y : y);  // reflect pad
            int r = y >> 3;
            float w = lanczos_w(s, q);
            if (r0 < 0) r0 = r;
            if (r == r0) va += w; else { r1 = r; vb += w; }
        }
        if (r1 < 0) r1 = r0;
        vA[s] = va; vB[s] = vb;
        vR0[s] = r0 - t + 1;   // index into imgL/Hs rows: 0..2
        vR1[s] = r1 - t + 1;
    }
    __syncthreads();

    // --- build 3 H rows: H[r,j] = a(j)*img[r,c0] + b(j)*img[r,c1] ---
    #pragma unroll
    for (int s = 0; s < 12; ++s) {            // 3*1024/256
        int id  = tid + (s << 8);
        int idx = id >> 10;                   // 0..2
        int jl  = id & 1023;
        int j   = j0 + jl;
        int phi = j & 7;
        float a, b; int c0, c1;
        if (j < 4)          { a = hS[phi]; b = 0.f;     c0 = 0;   c1 = 0;   }
        else if (j >= 2044) { a = hS[phi]; b = 0.f;     c0 = 255; c1 = 255; }
        else                { a = hA[phi]; b = hB[phi]; c0 = (j - 4) >> 3; c1 = c0 + 1; }
        Hs[idx][jl] = a * imgL[idx][c0] + b * imgL[idx][c1];
    }
    __syncthreads();

    // --- emit 8 output rows, float4 per thread per row ---
    float* outBase = out + (size_t)bc * (2048 * 2048);
    #pragma unroll
    for (int s = 0; s < 8; ++s) {
        int i = (t << 3) + s;
        float va = vA[s], vb = vB[s];
        const float4* h0 = (const float4*)&Hs[vR0[s]][0];
        const float4* h1 = (const float4*)&Hs[vR1[s]][0];
        float4 x0 = h0[tid];
        float4 x1 = h1[tid];
        float4 o;
        o.x = va * x0.x + vb * x1.x;
        o.y = va * x0.y + vb * x1.y;
        o.z = va * x0.z + vb * x1.z;
        o.w = va * x0.w + vb * x1.w;
        *(float4*)(outBase + (size_t)i * OW + j0 + (tid << 2)) = o;
    }
}

extern "C" void kernel_launch(void* const* d_in, const int* in_sizes, int n_in,
                              void* d_out, int out_size, void* d_ws, size_t ws_size,
                              hipStream_t stream) {
    const float* img = (const float*)d_in[0];
    float* out = (float*)d_out;
    // fixed problem geometry: (4,2,256,256) -> (4,2,2048,2048)
    dim3 grid(4096), block(256);
    hipLaunchKernelGGL(lanczos_up8_kernel, grid, block, 0, stream, img, out);
}

// Round 2
// 26.749 us; speedup vs baseline: 1.3551x; 1.3551x over previous
//
#include <hip/hip_runtime.h>

// Lanczos-4 8x upsample (4,2,256,256) -> (4,2,2048,2048), fully collapsed.
//
// Exact scale 8 => 8 weight phases; 9 taps span <=2 source rows/cols; the
// nearest-gather replication collapses the whole operator to a 2x2 stencil:
//   out[i,j] = va(i&7)*H(r0) + vb(i&7)*H(r1),  H(r) = wa(j&7)*I[r][c0] + wb(j&7)*I[r][c1]
// with r0=(i-4)>>3, c0=(j-4)>>3 (reflection at edges collapses to a single
// col/row with the full tap sum as weight).
//
// Weights are baked (double-precision hand evaluation of the reference's
// sin(pi t)/(pi t) * sin(pi t/4)/(pi t/4) table at delta = phase/8, grouped
// by source column). Accuracy ~1e-5 per weight -> ~2e-4 output perturbation,
// negligible vs the 0.0994 threshold (measured absmax was 0.0156).

// wa (left-column weight), per phase 0..7
#define WA0 0.0f
#define WA1 -0.03041110f
#define WA2 0.02753266f
#define WA3 -0.00827163f
#define WA4 1.00243180f
#define WA5 1.01040147f
#define WA6 0.97375330f
#define WA7 1.03080550f
// wb (right-column weight)
#define WB0 1.0f
#define WB1 1.02991210f
#define WB2 0.97065798f
#define WB3 1.00472265f
#define WB4 -0.00765906f
#define WB5 -0.01652347f
#define WB6 0.02047608f
#define WB7 -0.03455115f
// full tap sum (edge / reflected case: all 9 taps hit one source col/row)
#define WS0 1.0f
#define WS1 0.99950100f
#define WS2 0.99819064f
#define WS3 0.99645102f
#define WS4 0.99477274f
#define WS5 0.99387800f
#define WS6 0.99422938f
#define WS7 0.99625435f

__global__ __launch_bounds__(256) void lanczos_up8_kernel(
    const float* __restrict__ img, float* __restrict__ out)
{
    // grid: bid = bc(8) * 512 + t(256) * 2 + half(2)
    int bid  = blockIdx.x;
    int half = bid & 1;          // which 1024-col half of the output row
    int t    = (bid >> 1) & 255; // source row / output row-group
    int bc   = bid >> 9;         // fused batch*channel 0..7
    int tid  = threadIdx.x;

    int v = (half << 8) | tid;   // global 4-col output group, 0..511
    int P = v & 1;               // parity: phases 0..3 (P=0) or 4..7 (P=1)
    int m = v >> 1;              // source column group

    bool eL = (v == 0);          // j=0..3   : all taps reflect onto col 0
    bool eR = (v == 511);        // j=2044..7: all taps reflect onto col 255

    // horizontal weights for this lane's 4 phases (all-constant selects)
    float a0 = P ? WA4 : WA0, b0 = P ? WB4 : WB0;
    float a1 = P ? WA5 : WA1, b1 = P ? WB5 : WB1;
    float a2 = P ? WA6 : WA2, b2 = P ? WB6 : WB2;
    float a3 = P ? WA7 : WA3, b3 = P ? WB7 : WB3;
    if (eL) { a0 = WS0; a1 = WS1; a2 = WS2; a3 = WS3; b0 = b1 = b2 = b3 = 0.f; }
    if (eR) { a0 = WS4; a1 = WS5; a2 = WS6; a3 = WS7; b0 = b1 = b2 = b3 = 0.f; }

    int c0 = P ? m : m - 1;
    if (eL) c0 = 0;
    if (eR) c0 = 255;
    int c1 = (eL || eR) ? c0 : c0 + 1;

    int rm = t > 0   ? t - 1 : 0;    // block-uniform row indices (clamped)
    int rp = t < 255 ? t + 1 : 255;

    const float* base = img + bc * 65536;
    float i00 = base[rm * 256 + c0], i01 = base[rm * 256 + c1];
    float i10 = base[t  * 256 + c0], i11 = base[t  * 256 + c1];
    float i20 = base[rp * 256 + c0], i21 = base[rp * 256 + c1];

    // horizontally-filtered values for 3 source rows x 4 output cols
    float h00 = a0*i00 + b0*i01, h01 = a1*i00 + b1*i01, h02 = a2*i00 + b2*i01, h03 = a3*i00 + b3*i01;
    float h10 = a0*i10 + b0*i11, h11 = a1*i10 + b1*i11, h12 = a2*i10 + b2*i11, h13 = a3*i10 + b3*i11;
    float h20 = a0*i20 + b0*i21, h21 = a1*i20 + b1*i21, h22 = a2*i20 + b2*i21, h23 = a3*i20 + b3*i21;

    bool eT = (t == 0);     // rows 0..3   : all taps reflect onto row 0
    bool eB = (t == 255);   // rows 2044..7: all taps reflect onto row 255

    float* op = out + (size_t)bc * (2048 * 2048)
                    + (size_t)(t << 3) * 2048 + (half << 10) + (tid << 2);

    float va, vb; float4 o;
    // s<4: rows (t-1, t) -> (h0*, h1*);  s>=4: rows (t, t+1) -> (h1*, h2*)
#define EMIT(S, WAs, WBs, WSs, HX0,HX1,HX2,HX3, HY0,HY1,HY2,HY3, EDGE)   \
    va = (EDGE) ? WSs : WAs;  vb = (EDGE) ? 0.f : WBs;                   \
    o.x = va*HX0 + vb*HY0;  o.y = va*HX1 + vb*HY1;                       \
    o.z = va*HX2 + vb*HY2;  o.w = va*HX3 + vb*HY3;                       \
    *reinterpret_cast<float4*>(op + S * 2048) = o;

    EMIT(0, WA0, WB0, WS0, h00,h01,h02,h03, h10,h11,h12,h13, eT)
    EMIT(1, WA1, WB1, WS1, h00,h01,h02,h03, h10,h11,h12,h13, eT)
    EMIT(2, WA2, WB2, WS2, h00,h01,h02,h03, h10,h11,h12,h13, eT)
    EMIT(3, WA3, WB3, WS3, h00,h01,h02,h03, h10,h11,h12,h13, eT)
    EMIT(4, WA4, WB4, WS4, h10,h11,h12,h13, h20,h21,h22,h23, eB)
    EMIT(5, WA5, WB5, WS5, h10,h11,h12,h13, h20,h21,h22,h23, eB)
    EMIT(6, WA6, WB6, WS6, h10,h11,h12,h13, h20,h21,h22,h23, eB)
    EMIT(7, WA7, WB7, WS7, h10,h11,h12,h13, h20,h21,h22,h23, eB)
#undef EMIT
}

extern "C" void kernel_launch(void* const* d_in, const int* in_sizes, int n_in,
                              void* d_out, int out_size, void* d_ws, size_t ws_size,
                              hipStream_t stream) {
    const float* img = (const float*)d_in[0];
    float* out = (float*)d_out;
    dim3 grid(4096), block(256);
    hipLaunchKernelGGL(lanczos_up8_kernel, grid, block, 0, stream, img, out);
}